// Round 13
// baseline (68.515 us; speedup 1.0000x reference)
//
#include <hip/hip_runtime.h>

#define NQ 10

// Statevector layout (round-11 structure — 1 wave per batch element):
//   lane  = e & 63   (bits 5..0 = qubits 4..9)
//   reg r = e >> 6   (bits 9..6 = qubits 0..3), v2f v[16] per lane.
//
// Round-13: DS-pipe is the per-CU bottleneck (r12 evidence). Cut DS ops:
//   xor1 -> DPP 0xB1, xor2 -> 0x4E, xor8 -> row_ror:8 (0x128)      (VALU)
//   xor4 -> DPP chain: half_mirror(0x141)=xor7 then quad[3,2,1,0](0x1B)=xor3
//   xor16/xor32 -> permlane16/32_swap BUILTIN (VALU), direction-proof
//                  partner = r.x + r.y - own; __has_builtin fallback to
//                  the r10/r11 proven swizzle/bpermute path.
//   composed CNOT gather -> ds_bpermute (only remaining DS op: 32/layer)
//   epilogue: DPP row-butterfly + readlane cross-row (0 DS)

typedef float v2f __attribute__((ext_vector_type(2)));
typedef int   v2i __attribute__((ext_vector_type(2)));

#if __has_builtin(__builtin_amdgcn_permlane32_swap) && __has_builtin(__builtin_amdgcn_permlane16_swap)
#define HAVE_PLSWAP 1
#else
#define HAVE_PLSWAP 0
#endif

template<int CTRL>
__device__ __forceinline__ float dppf(float v) {
    const int i = __float_as_int(v);
    const int r = __builtin_amdgcn_update_dpp(i, i, CTRL, 0xF, 0xF, false);
    return __int_as_float(r);
}
template<int OFF>
__device__ __forceinline__ float swzf(float v) {
    return __int_as_float(__builtin_amdgcn_ds_swizzle(__float_as_int(v), OFF));
}
__device__ __forceinline__ float bpermf(int addr4, float v) {
    return __int_as_float(__builtin_amdgcn_ds_bpermute(addr4, __float_as_int(v)));
}
__device__ __forceinline__ float rdlane(float v, int l) {
    return __int_as_float(__builtin_amdgcn_readlane(__float_as_int(v), l));
}
// xor4 on the VALU: i^7 (half mirror) then i^3 (quad reverse) = i^4
__device__ __forceinline__ float xor4f(float v) {
    return dppf<0x1B>(dppf<0x141>(v));
}
// Partner fetch via permlane swap builtins. With both operands = x the
// per-lane result multiset {r.x, r.y} is {own, partner} under either swap
// direction, so partner = r.x + r.y - own (error <= 1 ulp).
__device__ __forceinline__ float pl32p(float x, int a32) {
#if HAVE_PLSWAP
    const int xi = __float_as_int(x);
    const v2i r = __builtin_amdgcn_permlane32_swap(xi, xi, false, false);
    return (__int_as_float(r.x) + __int_as_float(r.y)) - x;
#else
    return bpermf(a32, x);
#endif
}
__device__ __forceinline__ float pl16p(float x) {
#if HAVE_PLSWAP
    const int xi = __float_as_int(x);
    const v2i r = __builtin_amdgcn_permlane16_swap(xi, xi, false, false);
    return (__int_as_float(r.x) + __int_as_float(r.y)) - x;
#else
    return swzf<0x401F>(x);
#endif
}
__device__ __forceinline__ v2f splat(float a) { v2f r; r.x = a; r.y = a; return r; }
__device__ __forceinline__ v2f cmul(v2f a, v2f b) {
    v2f r;
    r.x = a.x * b.x - a.y * b.y;
    r.y = a.x * b.y + a.y * b.x;
    return r;
}

__global__ __launch_bounds__(256) void qnn_kernel(const float* __restrict__ x,
                                                  const float* __restrict__ w,
                                                  float* __restrict__ out,
                                                  int B) {
    const int lane = threadIdx.x & 63;
    const int b = blockIdx.x * 4 + (threadIdx.x >> 6);
    if (b >= B) return;

    // ---- angle tables: lanes 0..9 RX(x), lanes 0..39 RY weights ----
    float cxv = 1.f, sxv = 0.f, cwv = 1.f, swv = 0.f;
    if (lane < NQ) {
        const float a = 0.5f * x[b * NQ + lane];
        cxv = cosf(a); sxv = sinf(a);
    }
    if (lane < 4 * NQ) {
        const float a = 0.5f * w[lane];
        cwv = cosf(a); swv = sinf(a);
    }

    // ---- per-qubit 2-vectors after RX(x_q) then layer-0 RY(w0_q) ----
    v2f u0[NQ], u1[NQ];
#pragma unroll
    for (int q = 0; q < NQ; ++q) {
        const float c  = rdlane(cxv, q), s  = rdlane(sxv, q);
        const float ch = rdlane(cwv, q), sh = rdlane(swv, q);
        u0[q].x = ch * c;  u0[q].y = sh * s;
        u1[q].x = sh * c;  u1[q].y = -ch * s;
    }

    // ---- product state: amp(e) = prod_q u_q[bit_q(e)] ----
    v2f ml = (lane & 1) ? u1[9] : u0[9];
#pragma unroll
    for (int p = 1; p < 6; ++p) {
        const v2f f = ((lane >> p) & 1) ? u1[9 - p] : u0[9 - p];
        ml = cmul(ml, f);
    }
    v2f m01[4], m23[4], tml[4];
#pragma unroll
    for (int j = 0; j < 4; ++j) {
        m01[j] = cmul((j & 1) ? u1[3] : u0[3], (j & 2) ? u1[2] : u0[2]);
        m23[j] = cmul((j & 1) ? u1[1] : u0[1], (j & 2) ? u1[0] : u0[0]);
    }
#pragma unroll
    for (int j = 0; j < 4; ++j) tml[j] = cmul(ml, m01[j]);

    v2f v[16];
#pragma unroll
    for (int r = 0; r < 16; ++r) v[r] = cmul(tml[r & 3], m23[r >> 2]);

    // composed source lane for the q=4..8 CNOT chain; sigma_{q=3} folded:
    // odd regs gather from srcl^32.
    int t = lane;
    t ^= ((t >> 1) & 1) << 0;
    t ^= ((t >> 2) & 1) << 1;
    t ^= ((t >> 3) & 1) << 2;
    t ^= ((t >> 4) & 1) << 3;
    t ^= ((t >> 5) & 1) << 4;
    const int ga4 = t << 2;
    const int gb4 = (t ^ 32) << 2;
    const int a32 = (lane ^ 32) << 2;
    const bool wrapctl = (lane & 1);

    // ---- 3x { CNOT ring ; RY sweep(layer l+1) } ----
#pragma unroll
    for (int l = 0; l < 3; ++l) {
        // -- CNOT ring: q0,q1,q2 register renames --
        { v2f tmp;
          tmp = v[8];  v[8]  = v[12]; v[12] = tmp;
          tmp = v[9];  v[9]  = v[13]; v[13] = tmp;
          tmp = v[10]; v[10] = v[14]; v[14] = tmp;
          tmp = v[11]; v[11] = v[15]; v[15] = tmp; }
        { v2f tmp;
          tmp = v[4];  v[4]  = v[6];  v[6]  = tmp;
          tmp = v[5];  v[5]  = v[7];  v[7]  = tmp;
          tmp = v[12]; v[12] = v[14]; v[14] = tmp;
          tmp = v[13]; v[13] = v[15]; v[15] = tmp; }
        { v2f tmp;
          tmp = v[2];  v[2]  = v[3];  v[3]  = tmp;
          tmp = v[6];  v[6]  = v[7];  v[7]  = tmp;
          tmp = v[10]; v[10] = v[11]; v[11] = tmp;
          tmp = v[14]; v[14] = v[15]; v[15] = tmp; }
        // -- q3..q8 fused gather (the only DS op left) --
#pragma unroll
        for (int r = 0; r < 16; ++r) {
            const int a4 = (r & 1) ? gb4 : ga4;
            v[r].x = bpermf(a4, v[r].x);
            v[r].y = bpermf(a4, v[r].y);
        }
        // -- wrap: ctrl lane bit0, tgt rb3 --
#pragma unroll
        for (int r = 0; r < 8; ++r) {
            const v2f a = v[r], c2 = v[r + 8];
            v[r]     = wrapctl ? c2 : a;
            v[r + 8] = wrapctl ? a : c2;
        }

        // -- RY sweep, layer l+1 --
        const int base = (l + 1) * NQ;
        // q0..q3: register-local
#pragma unroll
        for (int q = 0; q < 4; ++q) {
            const v2f C = splat(rdlane(cwv, base + q));
            const v2f S = splat(rdlane(swv, base + q));
            const int m = 1 << (3 - q);
#pragma unroll
            for (int r = 0; r < 16; ++r) {
                if (!(r & m)) {
                    const int r1 = r | m;
                    const v2f a0 = v[r], a1 = v[r1];
                    v[r]  = C * a0 - S * a1;
                    v[r1] = S * a0 + C * a1;
                }
            }
        }
        // q4 (xor32): permlane32_swap
        {
            const float c = rdlane(cwv, base + 4);
            const float s = rdlane(swv, base + 4);
            const v2f C = splat(c);
            const v2f SS = splat((lane & 32) ? s : -s);
#pragma unroll
            for (int r = 0; r < 16; ++r) {
                v2f o; o.x = pl32p(v[r].x, a32); o.y = pl32p(v[r].y, a32);
                v[r] = C * v[r] + SS * o;
            }
        }
        // q5 (xor16): permlane16_swap
        {
            const float c = rdlane(cwv, base + 5);
            const float s = rdlane(swv, base + 5);
            const v2f C = splat(c);
            const v2f SS = splat((lane & 16) ? s : -s);
#pragma unroll
            for (int r = 0; r < 16; ++r) {
                v2f o; o.x = pl16p(v[r].x); o.y = pl16p(v[r].y);
                v[r] = C * v[r] + SS * o;
            }
        }
        // q6 (xor8): DPP row_ror:8
        {
            const float c = rdlane(cwv, base + 6);
            const float s = rdlane(swv, base + 6);
            const v2f C = splat(c);
            const v2f SS = splat((lane & 8) ? s : -s);
#pragma unroll
            for (int r = 0; r < 16; ++r) {
                v2f o; o.x = dppf<0x128>(v[r].x); o.y = dppf<0x128>(v[r].y);
                v[r] = C * v[r] + SS * o;
            }
        }
        // q7 (xor4): DPP chain (half_mirror + quad reverse)
        {
            const float c = rdlane(cwv, base + 7);
            const float s = rdlane(swv, base + 7);
            const v2f C = splat(c);
            const v2f SS = splat((lane & 4) ? s : -s);
#pragma unroll
            for (int r = 0; r < 16; ++r) {
                v2f o; o.x = xor4f(v[r].x); o.y = xor4f(v[r].y);
                v[r] = C * v[r] + SS * o;
            }
        }
        // q8 (xor2): DPP quad_perm [2,3,0,1]
        {
            const float c = rdlane(cwv, base + 8);
            const float s = rdlane(swv, base + 8);
            const v2f C = splat(c);
            const v2f SS = splat((lane & 2) ? s : -s);
#pragma unroll
            for (int r = 0; r < 16; ++r) {
                v2f o; o.x = dppf<0x4E>(v[r].x); o.y = dppf<0x4E>(v[r].y);
                v[r] = C * v[r] + SS * o;
            }
        }
        // q9 (xor1): DPP quad_perm [1,0,3,2]
        {
            const float c = rdlane(cwv, base + 9);
            const float s = rdlane(swv, base + 9);
            const v2f C = splat(c);
            const v2f SS = splat((lane & 1) ? s : -s);
#pragma unroll
            for (int r = 0; r < 16; ++r) {
                v2f o; o.x = dppf<0xB1>(v[r].x); o.y = dppf<0xB1>(v[r].y);
                v[r] = C * v[r] + SS * o;
            }
        }
    }

    // ---- measurement, ring-3 folded into signs (r11-validated mapping) ----
    float p[16];
#pragma unroll
    for (int r = 0; r < 16; ++r) p[r] = v[r].x * v[r].x + v[r].y * v[r].y;

    float S15 = 0.f, S7 = 0.f, S12 = 0.f, S14 = 0.f;
#pragma unroll
    for (int r = 0; r < 16; ++r) {
        const float pr = p[r];
        S15 += (__popc(r) & 1)      ? -pr : pr;
        S7  += (__popc(r & 7) & 1)  ? -pr : pr;
        S12 += (__popc(r & 12) & 1) ? -pr : pr;
        S14 += (__popc(r & 14) & 1) ? -pr : pr;
    }

    const float gAll = (__popc(lane) & 1) ? -1.f : 1.f;
    const float W7 = S15;
    float acc[NQ];
    acc[0] = gAll * S7;
    acc[1] = S12;
    acc[2] = S14;
    acc[3] = W7;
    acc[4] = ((lane >> 5) & 1) ? -W7 : W7;
    acc[5] = (__popc(lane & 0x30) & 1) ? -W7 : W7;
    acc[6] = (__popc(lane & 0x38) & 1) ? -W7 : W7;
    acc[7] = (__popc(lane & 0x3C) & 1) ? -W7 : W7;
    acc[8] = (__popc(lane & 0x3E) & 1) ? -W7 : W7;
    acc[9] = gAll * W7;

    // 64-lane reduce: DPP butterfly over bits 0-3, then readlane across rows
#pragma unroll
    for (int q = 0; q < NQ; ++q) {
        float a = acc[q];
        a += dppf<0x128>(a);   // xor8
        a += xor4f(a);         // xor4
        a += dppf<0x4E>(a);    // xor2
        a += dppf<0xB1>(a);    // xor1
        acc[q] = rdlane(a, 0) + rdlane(a, 16) + rdlane(a, 32) + rdlane(a, 48);
    }
    if (lane == 0) {
#pragma unroll
        for (int q = 0; q < NQ; ++q) out[b * NQ + q] = acc[q];
    }
}

extern "C" void kernel_launch(void* const* d_in, const int* in_sizes, int n_in,
                              void* d_out, int out_size, void* d_ws, size_t ws_size,
                              hipStream_t stream) {
    const float* x = (const float*)d_in[0];   // [B, 10]
    const float* w = (const float*)d_in[1];   // [40]
    float* out = (float*)d_out;               // [B, 10]
    const int B = in_sizes[0] / NQ;           // 2048
    qnn_kernel<<<(B + 3) / 4, 256, 0, stream>>>(x, w, out, B);
}